// Round 7
// baseline (156.974 us; speedup 1.0000x reference)
//
#include <hip/hip_runtime.h>
#include <hip/hip_bf16.h>
#include <stdint.h>

// SelfAttention B=8 H=8 S=2048 D=64 fp32, mask[B,S,S] int32 (0 -> -1e9).
// Round 7: loop-rotated software pipeline — QK(t+1) issued BEFORE softmax(t)
// so each wave's exp2/pack VALU overlaps its own QK MFMAs; mask folded into
// the QK MFMA C-in as a 0/-1e9 bias (select removed from the serial path);
// scA/scB register double-buffer. Keeps: depth-2 gload_lds prefetch with
// counted vmcnt(2) barriers, 4 LDS slots, max-free exp2 softmax, K/V bf16 +
// mask-bitpack prepass, ones-column denominator, setprio, XCD swizzle.

#define B_ 8
#define H_ 8
#define S_ 2048
#define D_ 64
#define QT 128
#define KT 64
#define NT (S_ / KT)
#define TILE_E (KT * D_)  // 4096 shorts = 8 KB per buffer slot
#define LOG2E 1.44269504088896340736f
#define QSCALE (0.125f * LOG2E)

typedef __bf16 bf16;
typedef bf16 bf16x8 __attribute__((ext_vector_type(8)));
typedef float f32x4 __attribute__((ext_vector_type(4)));
typedef unsigned short ushort8_t __attribute__((ext_vector_type(8)));
typedef unsigned long long u64;

#if __has_builtin(__builtin_amdgcn_exp2f)
#define EXP2(x) __builtin_amdgcn_exp2f(x)
#else
#define EXP2(x) exp2f(x)
#endif

static __device__ __forceinline__ unsigned short bfb(float f) {
    bf16 h = (bf16)f;  // RNE
    return __builtin_bit_cast(unsigned short, h);
}
// kv' bit-permutation: kv bits [b5 b4 b3 b2 b1 b0] -> kv' = [b5 b3 b2 b4 b1 b0].
static __device__ __forceinline__ int phi_inv(int c) {
    return ((c >> 5) & 1) * 32 + ((c >> 2) & 1) * 16 + ((c >> 4) & 1) * 8 +
           ((c >> 3) & 1) * 4 + (c & 3);
}
static __device__ __forceinline__ void gload16(const unsigned short* g, unsigned short* l) {
    __builtin_amdgcn_global_load_lds(
        (const __attribute__((address_space(1))) unsigned int*)g,
        (__attribute__((address_space(3))) unsigned int*)l, 16, 0, 0);
}

#define KV_BLOCKS (B_ * H_ * NT)  // 2048

// Fused prepass: blocks [0, KV_BLOCKS) convert K/V (if Ko != null); rest bitpack mask.
__global__ __launch_bounds__(256) void prep_fused(
    const float* __restrict__ K, const float* __restrict__ V,
    unsigned short* __restrict__ Ko, unsigned short* __restrict__ Vo,
    const int* __restrict__ M, u64* __restrict__ W) {
    const int tid = threadIdx.x;
    if (blockIdx.x >= KV_BLOCKS) {
        const int ln = tid & 63;
        const int w0 = (blockIdx.x - KV_BLOCKS) * 32 + (tid >> 6) * 8;
#pragma unroll
        for (int j = 0; j < 8; ++j) {
            const int v = M[(long)(w0 + j) * 64 + ln];
            const u64 bal = __ballot(v != 0);
            if (ln == 0) W[w0 + j] = bal;
        }
        return;
    }
    if (Ko == nullptr) return;
    __shared__ float Vl[64][65];
    const int t = blockIdx.x & (NT - 1);
    const int bh = blockIdx.x >> 5;
    const float* Kg = K + ((long)bh * S_ + t * 64) * D_;
    const float* Vg = V + ((long)bh * S_ + t * 64) * D_;
    unsigned short* Kout = Ko + ((long)bh * S_ + t * 64) * D_;
    unsigned short* Vout = Vo + (long)bh * D_ * S_ + t * 64;
    {   // K convert: 16 elems/thread
        const int kv = tid >> 2, d0 = (tid & 3) * 16;
#pragma unroll
        for (int half = 0; half < 2; ++half) {
            const float4 f0 = *(const float4*)(Kg + kv * D_ + d0 + half * 8);
            const float4 f1 = *(const float4*)(Kg + kv * D_ + d0 + half * 8 + 4);
            ushort8_t u;
            u[0] = bfb(f0.x); u[1] = bfb(f0.y); u[2] = bfb(f0.z); u[3] = bfb(f0.w);
            u[4] = bfb(f1.x); u[5] = bfb(f1.y); u[6] = bfb(f1.z); u[7] = bfb(f1.w);
            *(ushort8_t*)(Kout + kv * D_ + d0 + half * 8) = u;
        }
    }
    {   // V stage to LDS (coalesced reads)
#pragma unroll
        for (int i = 0; i < 4; ++i) {
            const int kv = i * 16 + (tid >> 4);
            const int d4 = (tid & 15) * 4;
            const float4 f = *(const float4*)(Vg + kv * D_ + d4);
            Vl[kv][d4 + 0] = f.x; Vl[kv][d4 + 1] = f.y;
            Vl[kv][d4 + 2] = f.z; Vl[kv][d4 + 3] = f.w;
        }
    }
    __syncthreads();
    {   // write transposed+permuted, coalesced ushort4 stores
#pragma unroll
        for (int j = 0; j < 4; ++j) {
            const int chunk = j * 256 + tid;
            const int d = chunk >> 4, q4 = chunk & 15;
            ushort4 w;
            w.x = bfb(Vl[phi_inv(q4 * 4 + 0)][d]);
            w.y = bfb(Vl[phi_inv(q4 * 4 + 1)][d]);
            w.z = bfb(Vl[phi_inv(q4 * 4 + 2)][d]);
            w.w = bfb(Vl[phi_inv(q4 * 4 + 3)][d]);
            *(ushort4*)(Vout + (long)d * S_ + q4 * 4) = w;
        }
    }
}

// ---- main kernel. MODE: 2=preconv+gload_lds pipeline, 1=reg-stage+bits, 0=reg-stage+raw ----
template <int MODE>
__global__ __launch_bounds__(512, 4) void attn_fwd(
    const float* __restrict__ Q, const float* __restrict__ K,
    const float* __restrict__ V, const int* __restrict__ M,
    const u64* __restrict__ W, const unsigned short* __restrict__ Kp,
    const unsigned short* __restrict__ Vp, float* __restrict__ O)
{
    __shared__ __attribute__((aligned(16))) unsigned short Ks3[4 * TILE_E];  // 32 KB
    __shared__ __attribute__((aligned(16))) unsigned short Vt3[4 * TILE_E];  // 32 KB

    const int tid = threadIdx.x;
    const int wv = tid >> 6, ln = tid & 63;
    const int col = ln & 15, grp = ln >> 4;

    int bid = blockIdx.x;
    bid = (bid & 7) * 128 + (bid >> 3);  // XCD chunk swizzle (1024 % 8 == 0, bijective)
    const int qt = bid & 15;
    const int h = (bid >> 4) & 7;
    const int b = bid >> 7;
    const int qw = qt * QT + wv * 16;

    // Q frag (B-operand): lane holds Q[q=col][d = c*32+grp*8+j] * QSCALE
    const float* Qg = Q + ((long)((b * H_ + h) * S_) + qw + col) * D_;
    bf16x8 qf[2];
#pragma unroll
    for (int c = 0; c < 2; ++c) {
        const float4 a0 = *(const float4*)(Qg + c * 32 + grp * 8);
        const float4 a1 = *(const float4*)(Qg + c * 32 + grp * 8 + 4);
        qf[c][0] = (bf16)(a0.x * QSCALE); qf[c][1] = (bf16)(a0.y * QSCALE);
        qf[c][2] = (bf16)(a0.z * QSCALE); qf[c][3] = (bf16)(a0.w * QSCALE);
        qf[c][4] = (bf16)(a1.x * QSCALE); qf[c][5] = (bf16)(a1.y * QSCALE);
        qf[c][6] = (bf16)(a1.z * QSCALE); qf[c][7] = (bf16)(a1.w * QSCALE);
    }
    bf16x8 onesf;
#pragma unroll
    for (int j = 0; j < 8; ++j) onesf[j] = (bf16)1.0f;

    f32x4 oacc[4];
#pragma unroll
    for (int i = 0; i < 4; ++i) oacc[i] = (f32x4){0.f, 0.f, 0.f, 0.f};
    f32x4 accs = (f32x4){0.f, 0.f, 0.f, 0.f};  // accs[r] = denominator for q=grp*4+r

    const u64* Wg = (MODE >= 1) ? (W + ((long)b * S_ + qw + col) * (S_ / 64)) : nullptr;
    const int* Mg = (MODE == 0) ? (M + ((long)b * S_ + qw + col) * S_) : nullptr;
    const unsigned short* Kbh = Kp + (long)(b * H_ + h) * S_ * D_;
    const unsigned short* Vbh = Vp + (long)(b * H_ + h) * D_ * S_;
    const float* Kf = K + (long)(b * H_ + h) * S_ * D_;
    const float* Vf = V + (long)(b * H_ + h) * S_ * D_;

    // MODE2 gload addressing: inverse-swizzled global source, linear LDS dest
    const int rl = ln >> 3;
    const int c8 = (ln & 7) ^ rl;
    const int krow = wv * 8 + rl;

    // MODE<=1 reg staging state
    float4 ka[2];
    float va[8];
    const int vd = ln, kg0 = wv;

    auto STAGE_ISSUE = [&](int kv0, int buf) {  // MODE2: 2 gload_lds/thread
        gload16(Kbh + (long)(kv0 + krow) * D_ + c8 * 8, Ks3 + buf * TILE_E + wv * 512);
        gload16(Vbh + (long)krow * S_ + kv0 + c8 * 8, Vt3 + buf * TILE_E + wv * 512);
    };
    auto LOADT = [&](int kv0) {  // MODE<=1
#pragma unroll
        for (int i = 0; i < 2; ++i) {
            const int idx4 = i * 512 + tid;
            const int row = idx4 >> 4, c4 = idx4 & 15;
            ka[i] = *(const float4*)(Kf + (long)(kv0 + row) * D_ + c4 * 4);
        }
#pragma unroll
        for (int i = 0; i < 2; ++i) {
            const int kg = kg0 + i * 8;
            const int kvn = phi_inv(kg * 4);
#pragma unroll
            for (int j = 0; j < 4; ++j)
                va[i * 4 + j] = Vf[(long)(kv0 + kvn + j) * D_ + vd];
        }
    };
    auto WRITET = [&](int buf) {  // MODE<=1
#pragma unroll
        for (int i = 0; i < 2; ++i) {
            const int idx4 = i * 512 + tid;
            const int row = idx4 >> 4, c4 = idx4 & 15;
            const int byte = (row * 128 + c4 * 8) ^ ((row & 7) << 4);
            ushort4 w;
            w.x = bfb(ka[i].x); w.y = bfb(ka[i].y);
            w.z = bfb(ka[i].z); w.w = bfb(ka[i].w);
            *(ushort4*)((char*)(Ks3 + buf * TILE_E) + byte) = w;
        }
#pragma unroll
        for (int i = 0; i < 2; ++i) {
            const int kg = kg0 + i * 8;
            const int byte = (vd * 128 + kg * 8) ^ ((vd & 7) << 4);
            ushort4 w;
            w.x = bfb(va[i * 4 + 0]); w.y = bfb(va[i * 4 + 1]);
            w.z = bfb(va[i * 4 + 2]); w.w = bfb(va[i * 4 + 3]);
            *(ushort4*)((char*)(Vt3 + buf * TILE_E) + byte) = w;
        }
    };

    // QK with mask bias as MFMA C-in: sc[blk][r] = (bit ? 0 : -1e9) + (K q)^T
    auto QKB = [&](u64 mwfull, const unsigned short* Kc, f32x4* sc) {
        const u64 mws = mwfull >> (grp * 4);
        const unsigned mlo = (unsigned)mws, mhi = (unsigned)(mws >> 32);
#pragma unroll
        for (int blk = 0; blk < 4; ++blk) {
            const unsigned w32 = (blk < 2) ? mlo : mhi;
#pragma unroll
            for (int r = 0; r < 4; ++r) {
                const int bit = (blk & 1) * 16 + r;  // compile-time
                sc[blk][r] = ((w32 >> bit) & 1u) ? 0.0f : -1e9f;
            }
        }
        __builtin_amdgcn_s_setprio(1);
#pragma unroll
        for (int blk = 0; blk < 4; ++blk) {
            const int row = blk * 16 + col;
            const int byte0 = (row * 128 + grp * 16) ^ ((row & 7) << 4);
            const int byte1 = (row * 128 + 64 + grp * 16) ^ ((row & 7) << 4);
            const bf16x8 kf0 = *(const bf16x8*)((const char*)Kc + byte0);
            const bf16x8 kf1 = *(const bf16x8*)((const char*)Kc + byte1);
            sc[blk] = __builtin_amdgcn_mfma_f32_16x16x32_bf16(kf0, qf[0], sc[blk], 0, 0, 0);
            sc[blk] = __builtin_amdgcn_mfma_f32_16x16x32_bf16(kf1, qf[1], sc[blk], 0, 0, 0);
        }
        __builtin_amdgcn_s_setprio(0);
    };
    // softmax (exp2, no max) + denominator + PV
    auto SMPV = [&](f32x4* sc, const unsigned short* Vc) {
        bf16x8 pf[2];
#pragma unroll
        for (int c = 0; c < 2; ++c)
#pragma unroll
            for (int j = 0; j < 8; ++j)
                pf[c][j] = (bf16)EXP2(sc[2 * c + (j >> 2)][j & 3]);
        __builtin_amdgcn_s_setprio(1);
        accs = __builtin_amdgcn_mfma_f32_16x16x32_bf16(pf[0], onesf, accs, 0, 0, 0);
        accs = __builtin_amdgcn_mfma_f32_16x16x32_bf16(pf[1], onesf, accs, 0, 0, 0);
#pragma unroll
        for (int c = 0; c < 2; ++c)
#pragma unroll
            for (int db = 0; db < 4; ++db) {
                const int vrow = db * 16 + col;
                const int byte = (vrow * 128 + c * 64 + grp * 16) ^ ((vrow & 7) << 4);
                const bf16x8 vf = *(const bf16x8*)((const char*)Vc + byte);
                oacc[db] = __builtin_amdgcn_mfma_f32_16x16x32_bf16(pf[c], vf, oacc[db], 0, 0, 0);
            }
        __builtin_amdgcn_s_setprio(0);
    };

#define WAIT2_BAR() do { asm volatile("s_waitcnt vmcnt(2)" ::: "memory"); \
    __builtin_amdgcn_s_barrier(); __builtin_amdgcn_sched_barrier(0); } while (0)
#define WAIT0_BAR() do { asm volatile("s_waitcnt vmcnt(0)" ::: "memory"); \
    __builtin_amdgcn_s_barrier(); __builtin_amdgcn_sched_barrier(0); } while (0)

    if (MODE == 2) {
        f32x4 scA[4], scB[4];
        // prologue: tiles 0,1 staged; compute sc(0); stage tile 2
        STAGE_ISSUE(0, 0);
        STAGE_ISSUE(KT, 1);
        WAIT2_BAR();                       // tile 0 ready (tile 1 may be in flight)
        {
            const u64 mw0 = Wg[0];
            QKB(mw0, Ks3, scA);
            STAGE_ISSUE(2 * KT, 2);
        }
        WAIT2_BAR();                       // tile 1 ready (tile 2 in flight)
        // steady state: t = 0 .. NT-5 in groups of 4 (slots compile-time)
#pragma unroll 1
        for (int tt = 0; tt < NT - 4; tt += 4) {
#pragma unroll
            for (int j = 0; j < 4; ++j) {
                const int t = tt + j;
                const u64 mwn = Wg[t + 1];
                STAGE_ISSUE((t + 3) * KT, (j + 3) & 3);
                if ((j & 1) == 0) {
                    QKB(mwn, Ks3 + ((j + 1) & 3) * TILE_E, scB);
                    SMPV(scA, Vt3 + j * TILE_E);
                } else {
                    QKB(mwn, Ks3 + ((j + 1) & 3) * TILE_E, scA);
                    SMPV(scB, Vt3 + j * TILE_E);
                }
                WAIT2_BAR();               // tile t+2 ready; t+3 stays in flight
            }
        }
        {   // tail: t = NT-4 .. NT-1 (28..31); scA holds sc(28)
            const u64 mw29 = Wg[NT - 3];
            STAGE_ISSUE((NT - 1) * KT, (NT - 1) & 3);       // tile 31 -> slot 3
            QKB(mw29, Ks3 + ((NT - 3) & 3) * TILE_E, scB);  // QK(29), slot 1
            SMPV(scA, Vt3 + ((NT - 4) & 3) * TILE_E);       // PV(28), slot 0
            WAIT2_BAR();                                    // tile 30 ready
            const u64 mw30 = Wg[NT - 2];
            QKB(mw30, Ks3 + ((NT - 2) & 3) * TILE_E, scA);  // QK(30), slot 2
            SMPV(scB, Vt3 + ((NT - 3) & 3) * TILE_E);       // PV(29), slot 1
            WAIT0_BAR();                                    // tile 31 ready
            const u64 mw31 = Wg[NT - 1];
            QKB(mw31, Ks3 + ((NT - 1) & 3) * TILE_E, scB);  // QK(31), slot 3
            SMPV(scA, Vt3 + ((NT - 2) & 3) * TILE_E);       // PV(30), slot 2
            SMPV(scB, Vt3 + ((NT - 1) & 3) * TILE_E);       // PV(31), slot 3
        }
    } else {
        // ---- fallback: 2-buffer, __syncthreads, select-based masking ----
        auto FSTEP = [&](u64 mwfull, int t, const unsigned short* Kc, const unsigned short* Vc) {
            f32x4 sc[4];
            const f32x4 zq = (f32x4){0.f, 0.f, 0.f, 0.f};
#pragma unroll
            for (int blk = 0; blk < 4; ++blk) {
                const int row = blk * 16 + col;
                const int byte0 = (row * 128 + grp * 16) ^ ((row & 7) << 4);
                const int byte1 = (row * 128 + 64 + grp * 16) ^ ((row & 7) << 4);
                const bf16x8 kf0 = *(const bf16x8*)((const char*)Kc + byte0);
                const bf16x8 kf1 = *(const bf16x8*)((const char*)Kc + byte1);
                sc[blk] = __builtin_amdgcn_mfma_f32_16x16x32_bf16(kf0, qf[0], zq, 0, 0, 0);
                sc[blk] = __builtin_amdgcn_mfma_f32_16x16x32_bf16(kf1, qf[1], sc[blk], 0, 0, 0);
            }
            bf16x8 pf[2];
            if (MODE >= 1) {
                const u64 mws = mwfull >> (grp * 4);
                const unsigned mlo = (unsigned)mws, mhi = (unsigned)(mws >> 32);
#pragma unroll
                for (int c = 0; c < 2; ++c)
#pragma unroll
                    for (int j = 0; j < 8; ++j) {
                        const int blk = 2 * c + (j >> 2), r = j & 3;
                        const unsigned w32 = (blk < 2) ? mlo : mhi;
                        const int bit = (blk & 1) * 16 + r;
                        const float s = ((w32 >> bit) & 1u) ? sc[blk][r] : -1e9f;
                        pf[c][j] = (bf16)EXP2(s);
                    }
            } else {
#pragma unroll
                for (int c = 0; c < 2; ++c)
#pragma unroll
                    for (int j = 0; j < 8; ++j) {
                        const int blk = 2 * c + (j >> 2), r = j & 3;
                        const int mv = Mg[t * KT + blk * 16 + grp * 4 + r];
                        const float s = mv ? sc[blk][r] : -1e9f;
                        pf[c][j] = (bf16)EXP2(s);
                    }
            }
            accs = __builtin_amdgcn_mfma_f32_16x16x32_bf16(pf[0], onesf, accs, 0, 0, 0);
            accs = __builtin_amdgcn_mfma_f32_16x16x32_bf16(pf[1], onesf, accs, 0, 0, 0);
#pragma unroll
            for (int c = 0; c < 2; ++c)
#pragma unroll
                for (int db = 0; db < 4; ++db) {
                    const int vrow = db * 16 + col;
                    const int byte = (vrow * 128 + c * 64 + grp * 16) ^ ((vrow & 7) << 4);
                    const bf16x8 vf = *(const bf16x8*)((const char*)Vc + byte);
                    oacc[db] = __builtin_amdgcn_mfma_f32_16x16x32_bf16(pf[c], vf, oacc[db], 0, 0, 0);
                }
        };
        LOADT(0);
        WRITET(0);
        __syncthreads();
#pragma unroll 1
        for (int t = 0; t < NT; t += 2) {
            if (t + 1 < NT) LOADT((t + 1) * KT);
            FSTEP(MODE >= 1 ? Wg[t] : 0ull, t, Ks3, Vt3);
            if (t + 1 < NT) WRITET(1);
            __syncthreads();
            if (t + 2 < NT) LOADT((t + 2) * KT);
            FSTEP(MODE >= 1 ? Wg[t + 1] : 0ull, t + 1, Ks3 + TILE_E, Vt3 + TILE_E);
            if (t + 2 < NT) WRITET(0);
            __syncthreads();
        }
    }

    // epilogue: accs[r] is the denominator, same layout as oacc — no shuffles
    float* Og = O + ((long)((b * H_ + h) * S_) + qw) * D_;
#pragma unroll
    for (int r = 0; r < 4; ++r) {
        const float inv = 1.0f / accs[r];
#pragma unroll
        for (int db = 0; db < 4; ++db)
            Og[(grp * 4 + r) * D_ + db * 16 + col] = oacc[db][r] * inv;
    }
#undef WAIT2_BAR
#undef WAIT0_BAR
}

extern "C" void kernel_launch(void* const* d_in, const int* in_sizes, int n_in,
                              void* d_out, int out_size, void* d_ws, size_t ws_size,
                              hipStream_t stream) {
    (void)in_sizes; (void)n_in; (void)out_size;
    const float* Q = (const float*)d_in[0];
    const float* K = (const float*)d_in[1];
    const float* V = (const float*)d_in[2];
    const int*   M = (const int*)d_in[3];
    float* O = (float*)d_out;

    const size_t szW = (size_t)B_ * S_ * (S_ / 64) * sizeof(u64);      // 4 MB
    const size_t szK = (size_t)B_ * H_ * S_ * D_ * 2;                  // 16 MB
    const int grid = B_ * H_ * (S_ / QT);                              // 1024
    const int nmaskblk = (B_ * S_ * (S_ / 64)) / 32;                   // 16384

    if (ws_size >= szW + 2 * szK) {
        u64* W = (u64*)d_ws;
        unsigned short* Kp = (unsigned short*)((char*)d_ws + szW);
        unsigned short* Vp = (unsigned short*)((char*)d_ws + szW + szK);
        prep_fused<<<KV_BLOCKS + nmaskblk, 256, 0, stream>>>(K, V, Kp, Vp, M, W);
        attn_fwd<2><<<grid, 512, 0, stream>>>(Q, K, V, M, W, Kp, Vp, O);
    } else if (ws_size >= szW) {
        u64* W = (u64*)d_ws;
        prep_fused<<<KV_BLOCKS + nmaskblk, 256, 0, stream>>>(K, V, nullptr, nullptr, M, W);
        attn_fwd<1><<<grid, 512, 0, stream>>>(Q, K, V, M, W, nullptr, nullptr, O);
    } else {
        attn_fwd<0><<<grid, 512, 0, stream>>>(Q, K, V, M, nullptr, nullptr, nullptr, O);
    }
}